// Round 1
// baseline (981.499 us; speedup 1.0000x reference)
//
#include <hip/hip_runtime.h>
#include <cstddef>
#include <cstdint>

#define C 256

// ---------------- histogram over dst ----------------
__global__ void hist_kernel(const int* __restrict__ dst, int* __restrict__ cnt, int E) {
    int e = blockIdx.x * blockDim.x + threadIdx.x;
    if (e < E) atomicAdd(&cnt[dst[e]], 1);
}

// ---------------- single-block exclusive scan (n <= ~64K) ----------------
__global__ __launch_bounds__(1024) void scan_kernel(const int* __restrict__ cnt,
                                                    int* __restrict__ off, int n) {
    __shared__ int buf[1024];
    int chunk = (n + 1023) >> 10;
    int lo = (int)threadIdx.x * chunk;
    int hi = min(lo + chunk, n);
    int s = 0;
    for (int i = lo; i < hi; ++i) s += cnt[i];
    buf[threadIdx.x] = s;
    __syncthreads();
    int xv = s;
    for (int d = 1; d < 1024; d <<= 1) {
        int t = ((int)threadIdx.x >= d) ? buf[threadIdx.x - d] : 0;
        __syncthreads();
        xv += t;
        buf[threadIdx.x] = xv;
        __syncthreads();
    }
    int run = xv - s;  // exclusive prefix of this thread's chunk
    for (int i = lo; i < hi; ++i) { off[i] = run; run += cnt[i]; }
}

// ---------------- scatter edge srcs into CSR order ----------------
__global__ void scatter_kernel(const int* __restrict__ src, const int* __restrict__ dst,
                               const int* __restrict__ off, int* __restrict__ cur,
                               int* __restrict__ esrc, int E) {
    int e = blockIdx.x * blockDim.x + threadIdx.x;
    if (e < E) {
        int d = dst[e];
        int p = off[d] + atomicAdd(&cur[d], 1);
        esrc[p] = src[e];
    }
}

// ---------------- mean aggregation (CSR), one wave per target ----------------
__global__ __launch_bounds__(256) void aggregate_kernel(const float4* __restrict__ x4,
        const int* __restrict__ esrc, const int* __restrict__ off,
        const int* __restrict__ cnt, float4* __restrict__ aggr4, int n_tgt) {
    int w = threadIdx.x >> 6;
    int lane = threadIdx.x & 63;
    int t = blockIdx.x * 4 + w;
    if (t >= n_tgt) return;
    int deg = cnt[t];
    int base = off[t];
    float4 acc = make_float4(0.f, 0.f, 0.f, 0.f);
    for (int i = 0; i < deg; ++i) {
        int s = esrc[base + i];
        float4 v = x4[(size_t)s * 64 + lane];
        acc.x += v.x; acc.y += v.y; acc.z += v.z; acc.w += v.w;
    }
    float inv = 1.0f / (float)(deg > 1 ? deg : 1);
    acc.x *= inv; acc.y *= inv; acc.z *= inv; acc.w *= inv;
    aggr4[(size_t)t * 64 + lane] = acc;
}

// ---------------- fused GEMM: h = relu(aggr@Wl^T + xt@Wr^T + b), + col stats ----------------
#define BM 64
#define BN 64
#define BK 16

__global__ __launch_bounds__(256) void gemm_bn_kernel(
        const float* __restrict__ Aagg, const float* __restrict__ Axt,
        const float* __restrict__ Wl, const float* __restrict__ Wr,
        const float* __restrict__ bias,
        float* __restrict__ h, float* __restrict__ colsum, float* __restrict__ colsq,
        int M) {
    __shared__ float As[BK][BM + 4];
    __shared__ float Bs[BK][BN + 4];
    __shared__ float csum[BN];
    __shared__ float csq[BN];

    const int tid = threadIdx.x;
    const int tx = tid & 15;
    const int ty = tid >> 4;
    const int n0 = blockIdx.x * BN;
    const int m0 = blockIdx.y * BM;

    if (tid < BN) { csum[tid] = 0.f; csq[tid] = 0.f; }

    const int am = tid >> 2;        // 0..63 (row within tile for staging)
    const int ak = (tid & 3) << 2;  // 0,4,8,12 (k within tile for staging)

    float acc[4][4];
#pragma unroll
    for (int i = 0; i < 4; ++i)
#pragma unroll
        for (int j = 0; j < 4; ++j) acc[i][j] = 0.f;

    for (int kt = 0; kt < 512; kt += BK) {
        const float* Asrc = (kt < 256) ? Aagg : Axt;
        const float* Bsrc = (kt < 256) ? Wl : Wr;
        const int k0 = kt & 255;
        float4 av = make_float4(0.f, 0.f, 0.f, 0.f);
        if (m0 + am < M)
            av = *(const float4*)&Asrc[(size_t)(m0 + am) * C + k0 + ak];
        float4 bv = *(const float4*)&Bsrc[(size_t)(n0 + am) * C + k0 + ak];
        __syncthreads();
        As[ak + 0][am] = av.x; As[ak + 1][am] = av.y;
        As[ak + 2][am] = av.z; As[ak + 3][am] = av.w;
        Bs[ak + 0][am] = bv.x; Bs[ak + 1][am] = bv.y;
        Bs[ak + 2][am] = bv.z; Bs[ak + 3][am] = bv.w;
        __syncthreads();
#pragma unroll
        for (int kk = 0; kk < BK; ++kk) {
            float4 a = *(const float4*)&As[kk][ty << 2];
            float4 b = *(const float4*)&Bs[kk][tx << 2];
            acc[0][0] += a.x * b.x; acc[0][1] += a.x * b.y; acc[0][2] += a.x * b.z; acc[0][3] += a.x * b.w;
            acc[1][0] += a.y * b.x; acc[1][1] += a.y * b.y; acc[1][2] += a.y * b.z; acc[1][3] += a.y * b.w;
            acc[2][0] += a.z * b.x; acc[2][1] += a.z * b.y; acc[2][2] += a.z * b.z; acc[2][3] += a.z * b.w;
            acc[3][0] += a.w * b.x; acc[3][1] += a.w * b.y; acc[3][2] += a.w * b.z; acc[3][3] += a.w * b.w;
        }
    }

    float4 bb = *(const float4*)&bias[n0 + (tx << 2)];
    float lsum[4] = {0.f, 0.f, 0.f, 0.f};
    float lsq[4]  = {0.f, 0.f, 0.f, 0.f};
#pragma unroll
    for (int i = 0; i < 4; ++i) {
        int m = m0 + (ty << 2) + i;
        if (m < M) {
            float4 c;
            c.x = fmaxf(acc[i][0] + bb.x, 0.f);
            c.y = fmaxf(acc[i][1] + bb.y, 0.f);
            c.z = fmaxf(acc[i][2] + bb.z, 0.f);
            c.w = fmaxf(acc[i][3] + bb.w, 0.f);
            *(float4*)&h[(size_t)m * C + n0 + (tx << 2)] = c;
            lsum[0] += c.x; lsum[1] += c.y; lsum[2] += c.z; lsum[3] += c.w;
            lsq[0] += c.x * c.x; lsq[1] += c.y * c.y; lsq[2] += c.z * c.z; lsq[3] += c.w * c.w;
        }
    }
#pragma unroll
    for (int j = 0; j < 4; ++j) {
        atomicAdd(&csum[(tx << 2) + j], lsum[j]);
        atomicAdd(&csq[(tx << 2) + j], lsq[j]);
    }
    __syncthreads();
    if (tid < BN) {
        atomicAdd(&colsum[n0 + tid], csum[tid]);
        atomicAdd(&colsq[n0 + tid], csq[tid]);
    }
}

// ---------------- batch-norm stat finalize ----------------
__global__ void finalize_kernel(const float* __restrict__ colsum, const float* __restrict__ colsq,
                                float* __restrict__ mu, float* __restrict__ rstd, float invN) {
    int c = threadIdx.x;
    float m = colsum[c] * invN;
    float v = colsq[c] * invN - m * m;
    mu[c] = m;
    rstd[c] = rsqrtf(fmaxf(v, 0.f) + 1e-5f);
}

// ---------------- normalize: out = g*(h-mu)*rstd + b ----------------
__global__ void normalize_kernel(const float4* __restrict__ hin,
                                 const float* __restrict__ mu, const float* __restrict__ rstd,
                                 const float* __restrict__ gamma, const float* __restrict__ beta,
                                 float4* __restrict__ outp, int n4) {
    int i = blockIdx.x * blockDim.x + threadIdx.x;
    if (i >= n4) return;
    int c = (i & 63) << 2;
    float4 v = hin[i];
    float4 m = *(const float4*)&mu[c];
    float4 r = *(const float4*)&rstd[c];
    float4 g = *(const float4*)&gamma[c];
    float4 b = *(const float4*)&beta[c];
    v.x = g.x * (v.x - m.x) * r.x + b.x;
    v.y = g.y * (v.y - m.y) * r.y + b.y;
    v.z = g.z * (v.z - m.z) * r.z + b.z;
    v.w = g.w * (v.w - m.w) * r.w + b.w;
    outp[i] = v;
}

extern "C" void kernel_launch(void* const* d_in, const int* in_sizes, int n_in,
                              void* d_out, int out_size, void* d_ws, size_t ws_size,
                              hipStream_t stream) {
    const float* x   = (const float*)d_in[0];
    const int* e0s   = (const int*)d_in[1];
    const int* e0d   = (const int*)d_in[2];
    const int* e1s   = (const int*)d_in[3];
    const int* e1d   = (const int*)d_in[4];
    const float* Wl0 = (const float*)d_in[5];
    const float* bl0 = (const float*)d_in[6];
    const float* Wr0 = (const float*)d_in[7];
    const float* ga0 = (const float*)d_in[8];
    const float* be0 = (const float*)d_in[9];
    const float* Wl1 = (const float*)d_in[10];
    const float* bl1 = (const float*)d_in[11];
    const float* Wr1 = (const float*)d_in[12];
    const float* ga1 = (const float*)d_in[13];
    const float* be1 = (const float*)d_in[14];

    const int N1 = 50000, N2 = 12500;
    const int E0 = in_sizes[1];   // 800000
    const int E1 = in_sizes[3];   // 400000

    char* ws = (char*)d_ws;
    size_t o = 0;
    auto alloc = [&](size_t bytes) -> char* {
        char* p = ws + o;
        o += (bytes + 255) & ~(size_t)255;
        return p;
    };

    int* cnt0 = (int*)alloc(2 * (size_t)N1 * sizeof(int)); int* cur0 = cnt0 + N1;
    int* off0 = (int*)alloc((size_t)N1 * sizeof(int));
    int* cnt1 = (int*)alloc(2 * (size_t)N2 * sizeof(int)); int* cur1 = cnt1 + N2;
    int* off1 = (int*)alloc((size_t)N2 * sizeof(int));
    int* esrc0 = (int*)alloc((size_t)E0 * sizeof(int));
    int* esrc1 = (int*)alloc((size_t)E1 * sizeof(int));
    float* stats = (float*)alloc(8 * C * sizeof(float));
    float* colsum0 = stats,         *colsq0 = stats + C;
    float* mu0     = stats + 2 * C, *rstd0  = stats + 3 * C;
    float* colsum1 = stats + 4 * C, *colsq1 = stats + 5 * C;
    float* mu1     = stats + 6 * C, *rstd1  = stats + 7 * C;
    float* h0    = (float*)alloc((size_t)N1 * C * sizeof(float));
    float* aggr0 = (float*)alloc((size_t)N1 * C * sizeof(float));
    // layer-1 buffers alias aggr0's region (dead after gemm0)
    float* aggr1 = aggr0;
    float* h1    = aggr0 + (size_t)N2 * C;

    hipMemsetAsync(cnt0, 0, 2 * (size_t)N1 * sizeof(int), stream);
    hipMemsetAsync(cnt1, 0, 2 * (size_t)N2 * sizeof(int), stream);
    hipMemsetAsync(stats, 0, 8 * C * sizeof(float), stream);

    // ---------------- layer 0 ----------------
    hist_kernel<<<(E0 + 255) / 256, 256, 0, stream>>>(e0d, cnt0, E0);
    scan_kernel<<<1, 1024, 0, stream>>>(cnt0, off0, N1);
    scatter_kernel<<<(E0 + 255) / 256, 256, 0, stream>>>(e0s, e0d, off0, cur0, esrc0, E0);
    aggregate_kernel<<<N1 / 4, 256, 0, stream>>>((const float4*)x, esrc0, off0, cnt0,
                                                 (float4*)aggr0, N1);
    dim3 grid0(C / BN, (N1 + BM - 1) / BM);
    gemm_bn_kernel<<<grid0, 256, 0, stream>>>(aggr0, x, Wl0, Wr0, bl0, h0, colsum0, colsq0, N1);
    finalize_kernel<<<1, C, 0, stream>>>(colsum0, colsq0, mu0, rstd0, 1.0f / (float)N1);
    int n4_0 = N1 * C / 4;
    normalize_kernel<<<(n4_0 + 255) / 256, 256, 0, stream>>>((const float4*)h0, mu0, rstd0,
                                                             ga0, be0, (float4*)h0, n4_0);

    // ---------------- layer 1 ----------------
    hist_kernel<<<(E1 + 255) / 256, 256, 0, stream>>>(e1d, cnt1, E1);
    scan_kernel<<<1, 1024, 0, stream>>>(cnt1, off1, N2);
    scatter_kernel<<<(E1 + 255) / 256, 256, 0, stream>>>(e1s, e1d, off1, cur1, esrc1, E1);
    aggregate_kernel<<<N2 / 4, 256, 0, stream>>>((const float4*)h0, esrc1, off1, cnt1,
                                                 (float4*)aggr1, N2);
    dim3 grid1(C / BN, (N2 + BM - 1) / BM);
    gemm_bn_kernel<<<grid1, 256, 0, stream>>>(aggr1, h0, Wl1, Wr1, bl1, h1, colsum1, colsq1, N2);
    finalize_kernel<<<1, C, 0, stream>>>(colsum1, colsq1, mu1, rstd1, 1.0f / (float)N2);
    int n4_1 = N2 * C / 4;
    normalize_kernel<<<(n4_1 + 255) / 256, 256, 0, stream>>>((const float4*)h1, mu1, rstd1,
                                                             ga1, be1, (float4*)d_out, n4_1);
}

// Round 2
// 791.780 us; speedup vs baseline: 1.2396x; 1.2396x over previous
//
#include <hip/hip_runtime.h>
#include <cstddef>
#include <cstdint>

#define C 256

typedef __attribute__((ext_vector_type(8))) short short8;
typedef __attribute__((ext_vector_type(4))) float f32x4;

__device__ __forceinline__ ushort f2bf(float f) {
    uint32_t u = __float_as_uint(f);
    u += 0x7FFF + ((u >> 16) & 1);   // round-to-nearest-even
    return (ushort)(u >> 16);
}
__device__ __forceinline__ float bf2f(ushort u) {
    return __uint_as_float(((uint32_t)u) << 16);
}
__device__ __forceinline__ uint2 pack4(float a, float b, float c, float d) {
    uint2 o;
    o.x = (uint32_t)f2bf(a) | ((uint32_t)f2bf(b) << 16);
    o.y = (uint32_t)f2bf(c) | ((uint32_t)f2bf(d) << 16);
    return o;
}

// ---------------- fp32 -> bf16 cast (vectorized) ----------------
__global__ void cast_kernel(const float4* __restrict__ src, uint2* __restrict__ dst, int n4) {
    int i = blockIdx.x * blockDim.x + threadIdx.x;
    if (i >= n4) return;
    float4 v = src[i];
    dst[i] = pack4(v.x, v.y, v.z, v.w);
}

// cast 4 weight matrices in one launch (blockIdx.y selects matrix)
__global__ void cast4_kernel(const float4* s0, const float4* s1,
                             const float4* s2, const float4* s3,
                             uint2* d0, uint2* d1, uint2* d2, uint2* d3, int n4) {
    int i = blockIdx.x * blockDim.x + threadIdx.x;
    if (i >= n4) return;
    const float4* s = (blockIdx.y == 0) ? s0 : (blockIdx.y == 1) ? s1 : (blockIdx.y == 2) ? s2 : s3;
    uint2* d = (blockIdx.y == 0) ? d0 : (blockIdx.y == 1) ? d1 : (blockIdx.y == 2) ? d2 : d3;
    float4 v = s[i];
    d[i] = pack4(v.x, v.y, v.z, v.w);
}

// ---------------- histogram over dst ----------------
__global__ void hist_kernel(const int* __restrict__ dst, int* __restrict__ cnt, int E) {
    int e = blockIdx.x * blockDim.x + threadIdx.x;
    if (e < E) atomicAdd(&cnt[dst[e]], 1);
}

// ---------------- single-block exclusive scan ----------------
__global__ __launch_bounds__(1024) void scan_kernel(const int* __restrict__ cnt,
                                                    int* __restrict__ off, int n) {
    __shared__ int buf[1024];
    int chunk = (n + 1023) >> 10;
    int lo = (int)threadIdx.x * chunk;
    int hi = min(lo + chunk, n);
    int s = 0;
    for (int i = lo; i < hi; ++i) s += cnt[i];
    buf[threadIdx.x] = s;
    __syncthreads();
    int xv = s;
    for (int d = 1; d < 1024; d <<= 1) {
        int t = ((int)threadIdx.x >= d) ? buf[threadIdx.x - d] : 0;
        __syncthreads();
        xv += t;
        buf[threadIdx.x] = xv;
        __syncthreads();
    }
    int run = xv - s;
    for (int i = lo; i < hi; ++i) { off[i] = run; run += cnt[i]; }
}

// ---------------- scatter edge srcs into CSR order ----------------
__global__ void scatter_kernel(const int* __restrict__ src, const int* __restrict__ dst,
                               const int* __restrict__ off, int* __restrict__ cur,
                               int* __restrict__ esrc, int E) {
    int e = blockIdx.x * blockDim.x + threadIdx.x;
    if (e < E) {
        int d = dst[e];
        int p = off[d] + atomicAdd(&cur[d], 1);
        esrc[p] = src[e];
    }
}

// ---------------- mean aggregation (CSR), bf16 input, bf16 output ----------------
__global__ __launch_bounds__(256) void aggregate_bf16_kernel(const uint2* __restrict__ xb,
        const int* __restrict__ esrc, const int* __restrict__ off,
        const int* __restrict__ cnt, uint2* __restrict__ aggr, int n_tgt) {
    int w = threadIdx.x >> 6;
    int lane = threadIdx.x & 63;
    int t = blockIdx.x * 4 + w;
    if (t >= n_tgt) return;
    int deg = cnt[t];
    int base = off[t];
    float ax = 0.f, ay = 0.f, az = 0.f, aw = 0.f;
    for (int i = 0; i < deg; ++i) {
        int s = esrc[base + i];
        uint2 v = xb[(size_t)s * 64 + lane];   // 4 bf16
        ax += bf2f((ushort)(v.x & 0xffff));
        ay += bf2f((ushort)(v.x >> 16));
        az += bf2f((ushort)(v.y & 0xffff));
        aw += bf2f((ushort)(v.y >> 16));
    }
    float inv = 1.0f / (float)(deg > 1 ? deg : 1);
    aggr[(size_t)t * 64 + lane] = pack4(ax * inv, ay * inv, az * inv, aw * inv);
}

// ---------------- mean aggregation (CSR), fp32 input, bf16 output (fallback) ----------------
__global__ __launch_bounds__(256) void aggregate_f32_kernel(const float4* __restrict__ x4,
        const int* __restrict__ esrc, const int* __restrict__ off,
        const int* __restrict__ cnt, uint2* __restrict__ aggr, int n_tgt) {
    int w = threadIdx.x >> 6;
    int lane = threadIdx.x & 63;
    int t = blockIdx.x * 4 + w;
    if (t >= n_tgt) return;
    int deg = cnt[t];
    int base = off[t];
    float4 acc = make_float4(0.f, 0.f, 0.f, 0.f);
    for (int i = 0; i < deg; ++i) {
        int s = esrc[base + i];
        float4 v = x4[(size_t)s * 64 + lane];
        acc.x += v.x; acc.y += v.y; acc.z += v.z; acc.w += v.w;
    }
    float inv = 1.0f / (float)(deg > 1 ? deg : 1);
    aggr[(size_t)t * 64 + lane] = pack4(acc.x * inv, acc.y * inv, acc.z * inv, acc.w * inv);
}

// ---------------- MFMA GEMM: h = relu([aggr|xt] @ [Wl;Wr]^T + b), bf16 out + col stats ----------------
#define TM 128
#define TN 128
#define LDK 40   // padded LDS row stride (elements); 80B = 5*16B keeps b128 alignment

__global__ __launch_bounds__(256) void gemm_bn_mfma(
        const ushort* __restrict__ Aagg, const ushort* __restrict__ Axt,
        const ushort* __restrict__ Wl,  const ushort* __restrict__ Wr,
        const float* __restrict__ bias,
        ushort* __restrict__ h, float* __restrict__ colsum, float* __restrict__ colsq,
        int M) {
    __shared__ ushort As[TM * LDK];
    __shared__ ushort Bs[TN * LDK];
    __shared__ float csum[TN];
    __shared__ float csq[TN];

    const int tid = threadIdx.x;
    const int m0 = blockIdx.y * TM;
    const int n0 = blockIdx.x * TN;
    const int wid = tid >> 6, lane = tid & 63;
    const int l15 = lane & 15, quad = lane >> 4;
    const int wm = (wid & 1) * 64, wn = (wid >> 1) * 64;

    if (tid < TN) { csum[tid] = 0.f; csq[tid] = 0.f; }

    const int srow = tid >> 2;      // 0..63
    const int skoff = (tid & 3) * 8; // 0,8,16,24 (elements)

    f32x4 acc[4][4];
#pragma unroll
    for (int i = 0; i < 4; ++i)
#pragma unroll
        for (int j = 0; j < 4; ++j) acc[i][j] = (f32x4){0.f, 0.f, 0.f, 0.f};

#pragma unroll 1
    for (int kt = 0; kt < 16; ++kt) {
        const int ks = kt * 32;
        const ushort* Ab = (ks < 256) ? Aagg : Axt;
        const ushort* Bb = (ks < 256) ? Wl : Wr;
        const int k0 = ks & 255;
        int r0 = min(m0 + srow, M - 1);
        int r1 = min(m0 + srow + 64, M - 1);
        uint4 a0 = *(const uint4*)&Ab[(size_t)r0 * C + k0 + skoff];
        uint4 a1 = *(const uint4*)&Ab[(size_t)r1 * C + k0 + skoff];
        uint4 b0 = *(const uint4*)&Bb[(size_t)(n0 + srow) * C + k0 + skoff];
        uint4 b1 = *(const uint4*)&Bb[(size_t)(n0 + srow + 64) * C + k0 + skoff];
        __syncthreads();
        *(uint4*)&As[srow * LDK + skoff] = a0;
        *(uint4*)&As[(srow + 64) * LDK + skoff] = a1;
        *(uint4*)&Bs[srow * LDK + skoff] = b0;
        *(uint4*)&Bs[(srow + 64) * LDK + skoff] = b1;
        __syncthreads();

        short8 af[4], bw[4];
#pragma unroll
        for (int mi = 0; mi < 4; ++mi)
            af[mi] = *(const short8*)&As[(wm + mi * 16 + l15) * LDK + quad * 8];
#pragma unroll
        for (int ni = 0; ni < 4; ++ni)
            bw[ni] = *(const short8*)&Bs[(wn + ni * 16 + l15) * LDK + quad * 8];
#pragma unroll
        for (int mi = 0; mi < 4; ++mi)
#pragma unroll
            for (int ni = 0; ni < 4; ++ni)
                acc[mi][ni] = __builtin_amdgcn_mfma_f32_16x16x32_bf16(
                    af[mi], bw[ni], acc[mi][ni], 0, 0, 0);
    }

    float lsum[4] = {0.f, 0.f, 0.f, 0.f};
    float lsq[4]  = {0.f, 0.f, 0.f, 0.f};
#pragma unroll
    for (int ni = 0; ni < 4; ++ni) {
        const int col = wn + ni * 16 + l15;
        const float bv = bias[n0 + col];
#pragma unroll
        for (int mi = 0; mi < 4; ++mi) {
#pragma unroll
            for (int r = 0; r < 4; ++r) {
                int m = m0 + wm + mi * 16 + quad * 4 + r;
                float v = acc[mi][ni][r] + bv;
                v = fmaxf(v, 0.f);
                if (m < M) {
                    h[(size_t)m * C + n0 + col] = f2bf(v);
                    lsum[ni] += v;
                    lsq[ni] += v * v;
                }
            }
        }
    }
#pragma unroll
    for (int ni = 0; ni < 4; ++ni) {
        const int col = wn + ni * 16 + l15;
        atomicAdd(&csum[col], lsum[ni]);
        atomicAdd(&csq[col], lsq[ni]);
    }
    __syncthreads();
    if (tid < TN) {
        atomicAdd(&colsum[n0 + tid], csum[tid]);
        atomicAdd(&colsq[n0 + tid], csq[tid]);
    }
}

// ---------------- batch-norm stat finalize ----------------
__global__ void finalize_kernel(const float* __restrict__ colsum, const float* __restrict__ colsq,
                                float* __restrict__ mu, float* __restrict__ rstd, float invN) {
    int c = threadIdx.x;
    float m = colsum[c] * invN;
    float v = colsq[c] * invN - m * m;
    mu[c] = m;
    rstd[c] = rsqrtf(fmaxf(v, 0.f) + 1e-5f);
}

// ---------------- normalize: bf16 in -> bf16 out ----------------
__global__ void norm_bf_kernel(const uint2* __restrict__ hin,
                               const float* __restrict__ mu, const float* __restrict__ rstd,
                               const float* __restrict__ gamma, const float* __restrict__ beta,
                               uint2* __restrict__ outp, int n4) {
    int i = blockIdx.x * blockDim.x + threadIdx.x;
    if (i >= n4) return;
    int c = (i & 63) << 2;
    uint2 v = hin[i];
    float4 m = *(const float4*)&mu[c];
    float4 r = *(const float4*)&rstd[c];
    float4 g = *(const float4*)&gamma[c];
    float4 b = *(const float4*)&beta[c];
    float x0 = g.x * (bf2f((ushort)(v.x & 0xffff)) - m.x) * r.x + b.x;
    float x1 = g.y * (bf2f((ushort)(v.x >> 16))    - m.y) * r.y + b.y;
    float x2 = g.z * (bf2f((ushort)(v.y & 0xffff)) - m.z) * r.z + b.z;
    float x3 = g.w * (bf2f((ushort)(v.y >> 16))    - m.w) * r.w + b.w;
    outp[i] = pack4(x0, x1, x2, x3);
}

// ---------------- normalize: bf16 in -> fp32 out ----------------
__global__ void norm_f32_kernel(const uint2* __restrict__ hin,
                                const float* __restrict__ mu, const float* __restrict__ rstd,
                                const float* __restrict__ gamma, const float* __restrict__ beta,
                                float4* __restrict__ outp, int n4) {
    int i = blockIdx.x * blockDim.x + threadIdx.x;
    if (i >= n4) return;
    int c = (i & 63) << 2;
    uint2 v = hin[i];
    float4 m = *(const float4*)&mu[c];
    float4 r = *(const float4*)&rstd[c];
    float4 g = *(const float4*)&gamma[c];
    float4 b = *(const float4*)&beta[c];
    float4 o;
    o.x = g.x * (bf2f((ushort)(v.x & 0xffff)) - m.x) * r.x + b.x;
    o.y = g.y * (bf2f((ushort)(v.x >> 16))    - m.y) * r.y + b.y;
    o.z = g.z * (bf2f((ushort)(v.y & 0xffff)) - m.z) * r.z + b.z;
    o.w = g.w * (bf2f((ushort)(v.y >> 16))    - m.w) * r.w + b.w;
    outp[i] = o;
}

extern "C" void kernel_launch(void* const* d_in, const int* in_sizes, int n_in,
                              void* d_out, int out_size, void* d_ws, size_t ws_size,
                              hipStream_t stream) {
    const float* x   = (const float*)d_in[0];
    const int* e0s   = (const int*)d_in[1];
    const int* e0d   = (const int*)d_in[2];
    const int* e1s   = (const int*)d_in[3];
    const int* e1d   = (const int*)d_in[4];
    const float* Wl0 = (const float*)d_in[5];
    const float* bl0 = (const float*)d_in[6];
    const float* Wr0 = (const float*)d_in[7];
    const float* ga0 = (const float*)d_in[8];
    const float* be0 = (const float*)d_in[9];
    const float* Wl1 = (const float*)d_in[10];
    const float* bl1 = (const float*)d_in[11];
    const float* Wr1 = (const float*)d_in[12];
    const float* ga1 = (const float*)d_in[13];
    const float* be1 = (const float*)d_in[14];

    const int N0 = 200000, N1 = 50000, N2 = 12500;
    const int E0 = in_sizes[1];   // 800000
    const int E1 = in_sizes[3];   // 400000

    char* ws = (char*)d_ws;
    size_t o = 0;
    auto alloc = [&](size_t bytes) -> char* {
        char* p = ws + o;
        o += (bytes + 255) & ~(size_t)255;
        return p;
    };

    // Does the workspace fit the full-x bf16 cast? (~185 MB vs ~108 MB fallback)
    const size_t common =
        (size_t)N1 * C * 2 * 3 /*aggr0,h0raw,h0bf*/ + (size_t)E0 * 4 + (size_t)E1 * 4 +
        3 * (size_t)N1 * 4 + 3 * (size_t)N2 * 4 + 8 * C * 4 + 4 * (size_t)C * C * 2 + 65536;
    const bool full = ws_size >= common + (size_t)N0 * C * 2;

    ushort* x_bf  = (ushort*)alloc((full ? (size_t)N0 : (size_t)N1) * C * 2); // xt0 lives here
    ushort* aggr0 = (ushort*)alloc((size_t)N1 * C * 2);
    ushort* h0raw = (ushort*)alloc((size_t)N1 * C * 2);
    ushort* h0bf  = (ushort*)alloc((size_t)N1 * C * 2);
    // layer-1 buffers alias aggr0 (dead after gemm0)
    ushort* aggr1 = aggr0;
    ushort* h1raw = aggr0 + (size_t)N2 * C;
    int* esrc0 = (int*)alloc((size_t)E0 * sizeof(int));
    int* esrc1 = (int*)alloc((size_t)E1 * sizeof(int));
    int* cnt0 = (int*)alloc(2 * (size_t)N1 * sizeof(int)); int* cur0 = cnt0 + N1;
    int* off0 = (int*)alloc((size_t)N1 * sizeof(int));
    int* cnt1 = (int*)alloc(2 * (size_t)N2 * sizeof(int)); int* cur1 = cnt1 + N2;
    int* off1 = (int*)alloc((size_t)N2 * sizeof(int));
    float* stats = (float*)alloc(8 * C * sizeof(float));
    float* colsum0 = stats,         *colsq0 = stats + C;
    float* mu0     = stats + 2 * C, *rstd0  = stats + 3 * C;
    float* colsum1 = stats + 4 * C, *colsq1 = stats + 5 * C;
    float* mu1     = stats + 6 * C, *rstd1  = stats + 7 * C;
    ushort* wbf = (ushort*)alloc(4 * (size_t)C * C * 2);
    ushort* wl0 = wbf, *wr0 = wbf + C * C, *wl1 = wbf + 2 * C * C, *wr1 = wbf + 3 * C * C;

    hipMemsetAsync(cnt0, 0, 2 * (size_t)N1 * sizeof(int), stream);
    hipMemsetAsync(cnt1, 0, 2 * (size_t)N2 * sizeof(int), stream);
    hipMemsetAsync(stats, 0, 8 * C * sizeof(float), stream);

    // casts
    {
        int nx4 = (full ? N0 : N1) * C / 4;
        cast_kernel<<<(nx4 + 255) / 256, 256, 0, stream>>>((const float4*)x, (uint2*)x_bf, nx4);
        int nw4 = C * C / 4;
        dim3 g((nw4 + 255) / 256, 4);
        cast4_kernel<<<g, 256, 0, stream>>>((const float4*)Wl0, (const float4*)Wr0,
                                            (const float4*)Wl1, (const float4*)Wr1,
                                            (uint2*)wl0, (uint2*)wr0, (uint2*)wl1, (uint2*)wr1, nw4);
    }

    // ---------------- layer 0 ----------------
    hist_kernel<<<(E0 + 255) / 256, 256, 0, stream>>>(e0d, cnt0, E0);
    scan_kernel<<<1, 1024, 0, stream>>>(cnt0, off0, N1);
    scatter_kernel<<<(E0 + 255) / 256, 256, 0, stream>>>(e0s, e0d, off0, cur0, esrc0, E0);
    if (full)
        aggregate_bf16_kernel<<<N1 / 4, 256, 0, stream>>>((const uint2*)x_bf, esrc0, off0, cnt0,
                                                          (uint2*)aggr0, N1);
    else
        aggregate_f32_kernel<<<N1 / 4, 256, 0, stream>>>((const float4*)x, esrc0, off0, cnt0,
                                                         (uint2*)aggr0, N1);
    dim3 grid0(C / TN, (N1 + TM - 1) / TM);
    gemm_bn_mfma<<<grid0, 256, 0, stream>>>(aggr0, x_bf, wl0, wr0, bl0,
                                            h0raw, colsum0, colsq0, N1);
    finalize_kernel<<<1, C, 0, stream>>>(colsum0, colsq0, mu0, rstd0, 1.0f / (float)N1);
    int n4_0 = N1 * C / 4;
    norm_bf_kernel<<<(n4_0 + 255) / 256, 256, 0, stream>>>((const uint2*)h0raw, mu0, rstd0,
                                                           ga0, be0, (uint2*)h0bf, n4_0);

    // ---------------- layer 1 ----------------
    hist_kernel<<<(E1 + 255) / 256, 256, 0, stream>>>(e1d, cnt1, E1);
    scan_kernel<<<1, 1024, 0, stream>>>(cnt1, off1, N2);
    scatter_kernel<<<(E1 + 255) / 256, 256, 0, stream>>>(e1s, e1d, off1, cur1, esrc1, E1);
    aggregate_bf16_kernel<<<N2 / 4, 256, 0, stream>>>((const uint2*)h0bf, esrc1, off1, cnt1,
                                                      (uint2*)aggr1, N2);
    dim3 grid1(C / TN, (N2 + TM - 1) / TM);
    gemm_bn_mfma<<<grid1, 256, 0, stream>>>(aggr1, h0bf, wl1, wr1, bl1,
                                            h1raw, colsum1, colsq1, N2);
    finalize_kernel<<<1, C, 0, stream>>>(colsum1, colsq1, mu1, rstd1, 1.0f / (float)N2);
    int n4_1 = N2 * C / 4;
    norm_f32_kernel<<<(n4_1 + 255) / 256, 256, 0, stream>>>((const uint2*)h1raw, mu1, rstd1,
                                                            ga1, be1, (float4*)d_out, n4_1);
}

// Round 3
// 707.636 us; speedup vs baseline: 1.3870x; 1.1189x over previous
//
#include <hip/hip_runtime.h>
#include <cstddef>
#include <cstdint>

#define C 256

typedef __attribute__((ext_vector_type(8))) short short8;
typedef __attribute__((ext_vector_type(4))) float f32x4;

__device__ __forceinline__ ushort f2bf(float f) {
    uint32_t u = __float_as_uint(f);
    u += 0x7FFF + ((u >> 16) & 1);   // round-to-nearest-even
    return (ushort)(u >> 16);
}
__device__ __forceinline__ float bf2f(ushort u) {
    return __uint_as_float(((uint32_t)u) << 16);
}
__device__ __forceinline__ uint2 pack4(float a, float b, float c, float d) {
    uint2 o;
    o.x = (uint32_t)f2bf(a) | ((uint32_t)f2bf(b) << 16);
    o.y = (uint32_t)f2bf(c) | ((uint32_t)f2bf(d) << 16);
    return o;
}
__device__ __forceinline__ void acc8(uint4 v, float* a) {
    a[0] += bf2f((ushort)(v.x & 0xffff)); a[1] += bf2f((ushort)(v.x >> 16));
    a[2] += bf2f((ushort)(v.y & 0xffff)); a[3] += bf2f((ushort)(v.y >> 16));
    a[4] += bf2f((ushort)(v.z & 0xffff)); a[5] += bf2f((ushort)(v.z >> 16));
    a[6] += bf2f((ushort)(v.w & 0xffff)); a[7] += bf2f((ushort)(v.w >> 16));
}

// ---------------- mega-prep: cast x, cast W0, hist0, hist1 ----------------
__global__ __launch_bounds__(256) void prep_kernel(
        const float4* __restrict__ x, int nx4, uint2* __restrict__ xbf,
        const float4* __restrict__ wl0f, const float4* __restrict__ wr0f,
        uint2* __restrict__ wl0b, uint2* __restrict__ wr0b,
        const int* __restrict__ e0d, int* __restrict__ cnt0, int E0,
        const int* __restrict__ e1d, int* __restrict__ cnt1, int E1) {
    const int stride = gridDim.x * blockDim.x;
    int i = blockIdx.x * blockDim.x + threadIdx.x;
    const int sec = blockIdx.y;
    if (sec == 0) {
        for (; i < nx4; i += stride) {
            float4 v = x[i];
            xbf[i] = pack4(v.x, v.y, v.z, v.w);
        }
    } else if (sec == 1) {
        const int nw4 = C * C / 4;
        for (; i < 2 * nw4; i += stride) {
            if (i < nw4) { float4 v = wl0f[i]; wl0b[i] = pack4(v.x, v.y, v.z, v.w); }
            else { float4 v = wr0f[i - nw4]; wr0b[i - nw4] = pack4(v.x, v.y, v.z, v.w); }
        }
    } else if (sec == 2) {
        for (; i < E0; i += stride) atomicAdd(&cnt0[e0d[i]], 1);
    } else {
        for (; i < E1; i += stride) atomicAdd(&cnt1[e1d[i]], 1);
    }
}

// ---------------- dual exclusive scan (block 0: layer 0, block 1: layer 1) ----------------
__global__ __launch_bounds__(1024) void scan2_kernel(
        const int* __restrict__ cnt0, int* __restrict__ off0, int n0,
        const int* __restrict__ cnt1, int* __restrict__ off1, int n1) {
    const int* cnt = blockIdx.x ? cnt1 : cnt0;
    int* off = blockIdx.x ? off1 : off0;
    int n = blockIdx.x ? n1 : n0;
    __shared__ int buf[1024];
    int chunk = (n + 1023) >> 10;
    int lo = (int)threadIdx.x * chunk;
    int hi = min(lo + chunk, n);
    int s = 0;
    for (int i = lo; i < hi; ++i) s += cnt[i];
    buf[threadIdx.x] = s;
    __syncthreads();
    int xv = s;
    for (int d = 1; d < 1024; d <<= 1) {
        int t = ((int)threadIdx.x >= d) ? buf[threadIdx.x - d] : 0;
        __syncthreads();
        xv += t;
        buf[threadIdx.x] = xv;
        __syncthreads();
    }
    int run = xv - s;
    for (int i = lo; i < hi; ++i) { off[i] = run; run += cnt[i]; }
}

// ---------------- fused scatter for both edge lists ----------------
__global__ void scatter2_kernel(
        const int* __restrict__ s0, const int* __restrict__ d0,
        const int* __restrict__ off0, int* __restrict__ cur0, int* __restrict__ esrc0, int E0,
        const int* __restrict__ s1, const int* __restrict__ d1,
        const int* __restrict__ off1, int* __restrict__ cur1, int* __restrict__ esrc1, int E1) {
    int e = blockIdx.x * blockDim.x + threadIdx.x;
    if (e < E0) {
        int d = d0[e];
        esrc0[off0[d] + atomicAdd(&cur0[d], 1)] = s0[e];
    } else if (e < E0 + E1) {
        int i = e - E0;
        int d = d1[i];
        esrc1[off1[d] + atomicAdd(&cur1[d], 1)] = s1[i];
    }
}

// ---------------- mean aggregation: one wave/target, 2 edges in flight, 16B/lane ----------------
__global__ __launch_bounds__(256) void aggregate_kernel(const uint4* __restrict__ xb4,
        const int* __restrict__ esrc, const int* __restrict__ off,
        const int* __restrict__ cnt, uint4* __restrict__ out4, int n_tgt) {
    const int lane = threadIdx.x & 63;
    const int half = lane >> 5, l31 = lane & 31;
    const int t = blockIdx.x * 4 + (threadIdx.x >> 6);
    if (t >= n_tgt) return;
    const int deg = cnt[t];
    const int base = off[t];
    float a[8] = {0.f, 0.f, 0.f, 0.f, 0.f, 0.f, 0.f, 0.f};
    const int deg2 = deg & ~1;
    for (int i = 0; i < deg2; i += 2) {
        int s = esrc[base + i + half];
        uint4 v = xb4[(size_t)s * 32 + l31];
        acc8(v, a);
    }
    if ((deg & 1) && half == 0) {
        int s = esrc[base + deg - 1];
        uint4 v = xb4[(size_t)s * 32 + l31];
        acc8(v, a);
    }
#pragma unroll
    for (int j = 0; j < 8; ++j) a[j] += __shfl_xor(a[j], 32, 64);
    if (half == 0) {
        float inv = 1.0f / (float)(deg > 1 ? deg : 1);
        uint4 o;
        o.x = (uint32_t)f2bf(a[0] * inv) | ((uint32_t)f2bf(a[1] * inv) << 16);
        o.y = (uint32_t)f2bf(a[2] * inv) | ((uint32_t)f2bf(a[3] * inv) << 16);
        o.z = (uint32_t)f2bf(a[4] * inv) | ((uint32_t)f2bf(a[5] * inv) << 16);
        o.w = (uint32_t)f2bf(a[6] * inv) | ((uint32_t)f2bf(a[7] * inv) << 16);
        out4[(size_t)t * 32 + l31] = o;
    }
}

// ---------------- fallback: fp32 gather -> bf16 aggr ----------------
__global__ __launch_bounds__(256) void aggregate_f32_kernel(const float4* __restrict__ x4,
        const int* __restrict__ esrc, const int* __restrict__ off,
        const int* __restrict__ cnt, uint2* __restrict__ aggr, int n_tgt) {
    int w = threadIdx.x >> 6;
    int lane = threadIdx.x & 63;
    int t = blockIdx.x * 4 + w;
    if (t >= n_tgt) return;
    int deg = cnt[t];
    int base = off[t];
    float4 acc = make_float4(0.f, 0.f, 0.f, 0.f);
    for (int i = 0; i < deg; ++i) {
        int s = esrc[base + i];
        float4 v = x4[(size_t)s * 64 + lane];
        acc.x += v.x; acc.y += v.y; acc.z += v.z; acc.w += v.w;
    }
    float inv = 1.0f / (float)(deg > 1 ? deg : 1);
    aggr[(size_t)t * 64 + lane] = pack4(acc.x * inv, acc.y * inv, acc.z * inv, acc.w * inv);
}

// ---------------- MFMA GEMM: h = relu([A|Axt] @ [Wl;Wr]^T + b), bf16 out + col stats ----------------
#define TM 128
#define TN 128
#define LDK 40

__global__ __launch_bounds__(256) void gemm_bn_mfma(
        const ushort* __restrict__ Aagg, const ushort* __restrict__ Axt,
        const ushort* __restrict__ Wl,  const ushort* __restrict__ Wr,
        const float* __restrict__ bias,
        ushort* __restrict__ h, float* __restrict__ colsum, float* __restrict__ colsq,
        int M) {
    __shared__ ushort As[TM * LDK];
    __shared__ ushort Bs[TN * LDK];
    __shared__ float csum[TN];
    __shared__ float csq[TN];

    const int tid = threadIdx.x;
    const int m0 = blockIdx.y * TM;
    const int n0 = blockIdx.x * TN;
    const int wid = tid >> 6, lane = tid & 63;
    const int l15 = lane & 15, quad = lane >> 4;
    const int wm = (wid & 1) * 64, wn = (wid >> 1) * 64;

    if (tid < TN) { csum[tid] = 0.f; csq[tid] = 0.f; }

    const int srow = tid >> 2;
    const int skoff = (tid & 3) * 8;

    f32x4 acc[4][4];
#pragma unroll
    for (int i = 0; i < 4; ++i)
#pragma unroll
        for (int j = 0; j < 4; ++j) acc[i][j] = (f32x4){0.f, 0.f, 0.f, 0.f};

#pragma unroll 1
    for (int kt = 0; kt < 16; ++kt) {
        const int ks = kt * 32;
        const ushort* Ab = (ks < 256) ? Aagg : Axt;
        const ushort* Bb = (ks < 256) ? Wl : Wr;
        const int k0 = ks & 255;
        int r0 = min(m0 + srow, M - 1);
        int r1 = min(m0 + srow + 64, M - 1);
        uint4 a0 = *(const uint4*)&Ab[(size_t)r0 * C + k0 + skoff];
        uint4 a1 = *(const uint4*)&Ab[(size_t)r1 * C + k0 + skoff];
        uint4 b0 = *(const uint4*)&Bb[(size_t)(n0 + srow) * C + k0 + skoff];
        uint4 b1 = *(const uint4*)&Bb[(size_t)(n0 + srow + 64) * C + k0 + skoff];
        __syncthreads();
        *(uint4*)&As[srow * LDK + skoff] = a0;
        *(uint4*)&As[(srow + 64) * LDK + skoff] = a1;
        *(uint4*)&Bs[srow * LDK + skoff] = b0;
        *(uint4*)&Bs[(srow + 64) * LDK + skoff] = b1;
        __syncthreads();

        short8 af[4], bw[4];
#pragma unroll
        for (int mi = 0; mi < 4; ++mi)
            af[mi] = *(const short8*)&As[(wm + mi * 16 + l15) * LDK + quad * 8];
#pragma unroll
        for (int ni = 0; ni < 4; ++ni)
            bw[ni] = *(const short8*)&Bs[(wn + ni * 16 + l15) * LDK + quad * 8];
#pragma unroll
        for (int mi = 0; mi < 4; ++mi)
#pragma unroll
            for (int ni = 0; ni < 4; ++ni)
                acc[mi][ni] = __builtin_amdgcn_mfma_f32_16x16x32_bf16(
                    af[mi], bw[ni], acc[mi][ni], 0, 0, 0);
    }

    float lsum[4] = {0.f, 0.f, 0.f, 0.f};
    float lsq[4]  = {0.f, 0.f, 0.f, 0.f};
#pragma unroll
    for (int ni = 0; ni < 4; ++ni) {
        const int col = wn + ni * 16 + l15;
        const float bv = bias[n0 + col];
#pragma unroll
        for (int mi = 0; mi < 4; ++mi) {
#pragma unroll
            for (int r = 0; r < 4; ++r) {
                int m = m0 + wm + mi * 16 + quad * 4 + r;
                float v = acc[mi][ni][r] + bv;
                v = fmaxf(v, 0.f);
                if (m < M) {
                    h[(size_t)m * C + n0 + col] = f2bf(v);
                    lsum[ni] += v;
                    lsq[ni] += v * v;
                }
            }
        }
    }
#pragma unroll
    for (int ni = 0; ni < 4; ++ni) {
        const int col = wn + ni * 16 + l15;
        atomicAdd(&csum[col], lsum[ni]);
        atomicAdd(&csq[col], lsq[ni]);
    }
    __syncthreads();
    if (tid < TN) {
        atomicAdd(&colsum[n0 + tid], csum[tid]);
        atomicAdd(&colsq[n0 + tid], csq[tid]);
    }
}

// ---------------- fixup: fold norm0 into layer-1 weights/bias ----------------
// s_k = g0_k * rsqrt(var_k+eps); t_k = be0_k - mu_k*s_k
// Wl1'[n,k] = Wl1[n,k]*s_k ; Wr1' likewise ; bias1'[n] = bl1[n] + sum_k t_k*(Wl1[n,k]+Wr1[n,k])
__global__ __launch_bounds__(256) void fixup_kernel(
        const float* __restrict__ colsum, const float* __restrict__ colsq, float invN,
        const float* __restrict__ g0, const float* __restrict__ be0,
        const float* __restrict__ Wl1, const float* __restrict__ Wr1,
        const float* __restrict__ bl1,
        ushort* __restrict__ wl1b, ushort* __restrict__ wr1b, float* __restrict__ bias1) {
    __shared__ float ss[C], st[C];
    __shared__ float red[256];
    const int k = threadIdx.x;
    {
        float m = colsum[k] * invN;
        float v = colsq[k] * invN - m * m;
        float r = rsqrtf(fmaxf(v, 0.f) + 1e-5f);
        float s = g0[k] * r;
        ss[k] = s;
        st[k] = be0[k] - m * s;
    }
    __syncthreads();
    const int n = blockIdx.x;
    float wl = Wl1[(size_t)n * C + k];
    float wr = Wr1[(size_t)n * C + k];
    wl1b[(size_t)n * C + k] = f2bf(wl * ss[k]);
    wr1b[(size_t)n * C + k] = f2bf(wr * ss[k]);
    red[k] = st[k] * (wl + wr);
    __syncthreads();
    for (int d = 128; d > 0; d >>= 1) {
        if (k < d) red[k] += red[k + d];
        __syncthreads();
    }
    if (k == 0) bias1[n] = bl1[n] + red[0];
}

// ---------------- norm1 (+ fused stat finalize): bf16 in -> fp32 out ----------------
__global__ __launch_bounds__(256) void norm1_kernel(const uint2* __restrict__ hin,
        const float* __restrict__ colsum, const float* __restrict__ colsq, float invN,
        const float* __restrict__ gamma, const float* __restrict__ beta,
        float4* __restrict__ outp, int n4) {
    __shared__ float smu[C], srs[C];
    {
        int k = threadIdx.x;
        float m = colsum[k] * invN;
        float v = colsq[k] * invN - m * m;
        smu[k] = m;
        srs[k] = rsqrtf(fmaxf(v, 0.f) + 1e-5f);
    }
    __syncthreads();
    int i = blockIdx.x * blockDim.x + threadIdx.x;
    if (i >= n4) return;
    int c = (i & 63) << 2;
    uint2 v = hin[i];
    float4 o;
    o.x = gamma[c + 0] * (bf2f((ushort)(v.x & 0xffff)) - smu[c + 0]) * srs[c + 0] + beta[c + 0];
    o.y = gamma[c + 1] * (bf2f((ushort)(v.x >> 16))    - smu[c + 1]) * srs[c + 1] + beta[c + 1];
    o.z = gamma[c + 2] * (bf2f((ushort)(v.y & 0xffff)) - smu[c + 2]) * srs[c + 2] + beta[c + 2];
    o.w = gamma[c + 3] * (bf2f((ushort)(v.y >> 16))    - smu[c + 3]) * srs[c + 3] + beta[c + 3];
    outp[i] = o;
}

extern "C" void kernel_launch(void* const* d_in, const int* in_sizes, int n_in,
                              void* d_out, int out_size, void* d_ws, size_t ws_size,
                              hipStream_t stream) {
    const float* x   = (const float*)d_in[0];
    const int* e0s   = (const int*)d_in[1];
    const int* e0d   = (const int*)d_in[2];
    const int* e1s   = (const int*)d_in[3];
    const int* e1d   = (const int*)d_in[4];
    const float* Wl0 = (const float*)d_in[5];
    const float* bl0 = (const float*)d_in[6];
    const float* Wr0 = (const float*)d_in[7];
    const float* ga0 = (const float*)d_in[8];
    const float* be0 = (const float*)d_in[9];
    const float* Wl1 = (const float*)d_in[10];
    const float* bl1 = (const float*)d_in[11];
    const float* Wr1 = (const float*)d_in[12];
    const float* ga1 = (const float*)d_in[13];
    const float* be1 = (const float*)d_in[14];

    const int N0 = 200000, N1 = 50000, N2 = 12500;
    const int E0 = in_sizes[1];
    const int E1 = in_sizes[3];

    char* ws = (char*)d_ws;
    size_t o = 0;
    auto alloc = [&](size_t bytes) -> char* {
        char* p = ws + o;
        o += (bytes + 255) & ~(size_t)255;
        return p;
    };

    const size_t common =
        (size_t)N1 * C * 2 * 2 /*aggr0,h0raw*/ + (size_t)E0 * 4 + (size_t)E1 * 4 +
        3 * (size_t)N1 * 4 + 3 * (size_t)N2 * 4 + 8 * C * 4 + 4 * (size_t)C * C * 2 +
        C * 4 + 65536;
    const bool full = ws_size >= common + (size_t)N0 * C * 2;

    ushort* x_bf  = (ushort*)alloc((full ? (size_t)N0 : (size_t)N1) * C * 2);
    ushort* aggr0 = (ushort*)alloc((size_t)N1 * C * 2);
    ushort* h0raw = (ushort*)alloc((size_t)N1 * C * 2);
    ushort* aggr1 = aggr0;                       // aggr0 dead after gemm0
    ushort* h1raw = aggr0 + (size_t)N2 * C;
    int* esrc0 = (int*)alloc((size_t)E0 * sizeof(int));
    int* esrc1 = (int*)alloc((size_t)E1 * sizeof(int));
    int* cnt0 = (int*)alloc(2 * (size_t)N1 * sizeof(int)); int* cur0 = cnt0 + N1;
    int* off0 = (int*)alloc((size_t)N1 * sizeof(int));
    int* cnt1 = (int*)alloc(2 * (size_t)N2 * sizeof(int)); int* cur1 = cnt1 + N2;
    int* off1 = (int*)alloc((size_t)N2 * sizeof(int));
    float* stats = (float*)alloc(8 * C * sizeof(float));
    float* colsum0 = stats,         *colsq0 = stats + C;
    float* colsum1 = stats + 4 * C, *colsq1 = stats + 5 * C;
    ushort* wbf = (ushort*)alloc(4 * (size_t)C * C * 2);
    ushort* wl0b = wbf, *wr0b = wbf + C * C, *wl1b = wbf + 2 * C * C, *wr1b = wbf + 3 * C * C;
    float* bias1 = (float*)alloc(C * sizeof(float));

    hipMemsetAsync(cnt0, 0, 2 * (size_t)N1 * sizeof(int), stream);
    hipMemsetAsync(cnt1, 0, 2 * (size_t)N2 * sizeof(int), stream);
    hipMemsetAsync(stats, 0, 8 * C * sizeof(float), stream);

    // prep: cast x + cast W0 + hist0 + hist1
    {
        int nx4 = (full ? N0 : N1) * C / 4;
        dim3 g(2048, 4);
        prep_kernel<<<g, 256, 0, stream>>>((const float4*)x, nx4, (uint2*)x_bf,
                                           (const float4*)Wl0, (const float4*)Wr0,
                                           (uint2*)wl0b, (uint2*)wr0b,
                                           e0d, cnt0, E0, e1d, cnt1, E1);
    }
    scan2_kernel<<<2, 1024, 0, stream>>>(cnt0, off0, N1, cnt1, off1, N2);
    scatter2_kernel<<<(E0 + E1 + 255) / 256, 256, 0, stream>>>(
        e0s, e0d, off0, cur0, esrc0, E0, e1s, e1d, off1, cur1, esrc1, E1);

    // ---------------- layer 0 ----------------
    if (full)
        aggregate_kernel<<<N1 / 4, 256, 0, stream>>>((const uint4*)x_bf, esrc0, off0, cnt0,
                                                     (uint4*)aggr0, N1);
    else
        aggregate_f32_kernel<<<N1 / 4, 256, 0, stream>>>((const float4*)x, esrc0, off0, cnt0,
                                                         (uint2*)aggr0, N1);
    dim3 grid0(C / TN, (N1 + TM - 1) / TM);
    gemm_bn_mfma<<<grid0, 256, 0, stream>>>(aggr0, x_bf, wl0b, wr0b, bl0,
                                            h0raw, colsum0, colsq0, N1);
    // fold norm0 into layer-1 weights/bias
    fixup_kernel<<<C, 256, 0, stream>>>(colsum0, colsq0, 1.0f / (float)N1,
                                        ga0, be0, Wl1, Wr1, bl1, wl1b, wr1b, bias1);

    // ---------------- layer 1 (operates on RAW h0) ----------------
    aggregate_kernel<<<N2 / 4, 256, 0, stream>>>((const uint4*)h0raw, esrc1, off1, cnt1,
                                                 (uint4*)aggr1, N2);
    dim3 grid1(C / TN, (N2 + TM - 1) / TM);
    gemm_bn_mfma<<<grid1, 256, 0, stream>>>(aggr1, h0raw, wl1b, wr1b, bias1,
                                            h1raw, colsum1, colsq1, N2);
    int n4_1 = N2 * C / 4;
    norm1_kernel<<<(n4_1 + 255) / 256, 256, 0, stream>>>((const uint2*)h1raw,
                                                         colsum1, colsq1, 1.0f / (float)N2,
                                                         ga1, be1, (float4*)d_out, n4_1);
}

// Round 4
// 686.078 us; speedup vs baseline: 1.4306x; 1.0314x over previous
//
#include <hip/hip_runtime.h>
#include <cstddef>
#include <cstdint>

#define C 256

typedef __attribute__((ext_vector_type(8))) short short8;
typedef __attribute__((ext_vector_type(4))) float f32x4;

__device__ __forceinline__ ushort f2bf(float f) {
    uint32_t u = __float_as_uint(f);
    u += 0x7FFF + ((u >> 16) & 1);   // round-to-nearest-even
    return (ushort)(u >> 16);
}
__device__ __forceinline__ float bf2f(ushort u) {
    return __uint_as_float(((uint32_t)u) << 16);
}
__device__ __forceinline__ uint2 pack4(float a, float b, float c, float d) {
    uint2 o;
    o.x = (uint32_t)f2bf(a) | ((uint32_t)f2bf(b) << 16);
    o.y = (uint32_t)f2bf(c) | ((uint32_t)f2bf(d) << 16);
    return o;
}
__device__ __forceinline__ uint4 pack8(float4 a, float4 b) {
    uint4 o;
    o.x = (uint32_t)f2bf(a.x) | ((uint32_t)f2bf(a.y) << 16);
    o.y = (uint32_t)f2bf(a.z) | ((uint32_t)f2bf(a.w) << 16);
    o.z = (uint32_t)f2bf(b.x) | ((uint32_t)f2bf(b.y) << 16);
    o.w = (uint32_t)f2bf(b.z) | ((uint32_t)f2bf(b.w) << 16);
    return o;
}
__device__ __forceinline__ void acc8(uint4 v, float* a) {
    a[0] += bf2f((ushort)(v.x & 0xffff)); a[1] += bf2f((ushort)(v.x >> 16));
    a[2] += bf2f((ushort)(v.y & 0xffff)); a[3] += bf2f((ushort)(v.y >> 16));
    a[4] += bf2f((ushort)(v.z & 0xffff)); a[5] += bf2f((ushort)(v.z >> 16));
    a[6] += bf2f((ushort)(v.w & 0xffff)); a[7] += bf2f((ushort)(v.w >> 16));
}

// ---------------- mega-prep, flat work-proportional grid ----------------
// blocks [0,6400): cast x (8 elem/lane/iter)
// blocks [6400,6464): cast Wl0+Wr0
// blocks [6464,7488): hist0
// blocks [7488,8000): hist1
#define PB_CAST 6400
#define PB_W    64
#define PB_H0   1024
#define PB_H1   512

__global__ __launch_bounds__(256) void prep_kernel(
        const float4* __restrict__ x4, int nx8, uint4* __restrict__ xbf4,
        const float4* __restrict__ wl0f, const float4* __restrict__ wr0f,
        uint4* __restrict__ wl0b, uint4* __restrict__ wr0b,
        const int* __restrict__ e0d, int* __restrict__ cnt0, int E0,
        const int* __restrict__ e1d, int* __restrict__ cnt1, int E1) {
    const int b = blockIdx.x;
    if (b < PB_CAST) {
        const int stride = PB_CAST * 256;
        for (int i = b * 256 + threadIdx.x; i < nx8; i += stride) {
            float4 lo = x4[2 * (size_t)i];
            float4 hi = x4[2 * (size_t)i + 1];
            xbf4[i] = pack8(lo, hi);
        }
    } else if (b < PB_CAST + PB_W) {
        const int nw8 = C * C / 8;   // 8192 per matrix
        const int stride = PB_W * 256;
        for (int i = (b - PB_CAST) * 256 + threadIdx.x; i < 2 * nw8; i += stride) {
            if (i < nw8) {
                float4 lo = wl0f[2 * i], hi = wl0f[2 * i + 1];
                wl0b[i] = pack8(lo, hi);
            } else {
                int j = i - nw8;
                float4 lo = wr0f[2 * j], hi = wr0f[2 * j + 1];
                wr0b[j] = pack8(lo, hi);
            }
        }
    } else if (b < PB_CAST + PB_W + PB_H0) {
        const int stride = PB_H0 * 256;
        for (int i = (b - PB_CAST - PB_W) * 256 + threadIdx.x; i < E0; i += stride)
            atomicAdd(&cnt0[e0d[i]], 1);
    } else {
        const int stride = PB_H1 * 256;
        for (int i = (b - PB_CAST - PB_W - PB_H0) * 256 + threadIdx.x; i < E1; i += stride)
            atomicAdd(&cnt1[e1d[i]], 1);
    }
}

// ---------------- dual exclusive scan, writes off[n] sentinel ----------------
__global__ __launch_bounds__(1024) void scan2_kernel(
        const int* __restrict__ cnt0, int* __restrict__ off0, int n0,
        const int* __restrict__ cnt1, int* __restrict__ off1, int n1) {
    const int* cnt = blockIdx.x ? cnt1 : cnt0;
    int* off = blockIdx.x ? off1 : off0;
    int n = blockIdx.x ? n1 : n0;
    __shared__ int buf[1024];
    int chunk = (n + 1023) >> 10;
    int lo = (int)threadIdx.x * chunk;
    int hi = min(lo + chunk, n);
    int s = 0;
    for (int i = lo; i < hi; ++i) s += cnt[i];
    buf[threadIdx.x] = s;
    __syncthreads();
    int xv = s;
    for (int d = 1; d < 1024; d <<= 1) {
        int t = ((int)threadIdx.x >= d) ? buf[threadIdx.x - d] : 0;
        __syncthreads();
        xv += t;
        buf[threadIdx.x] = xv;
        __syncthreads();
    }
    int run = xv - s;
    for (int i = lo; i < hi; ++i) { off[i] = run; run += cnt[i]; }
    if (lo < n && hi == n) off[n] = run;   // sentinel (total)
}

// ---------------- fused scatter; cnt used as decrementing cursor ----------------
__global__ void scatter2_kernel(
        const int* __restrict__ s0, const int* __restrict__ d0,
        const int* __restrict__ off0, int* __restrict__ cnt0, int* __restrict__ esrc0, int E0,
        const int* __restrict__ s1, const int* __restrict__ d1,
        const int* __restrict__ off1, int* __restrict__ cnt1, int* __restrict__ esrc1, int E1) {
    int e = blockIdx.x * blockDim.x + threadIdx.x;
    if (e < E0) {
        int d = d0[e];
        int old = atomicSub(&cnt0[d], 1);
        esrc0[off0[d] + old - 1] = s0[e];
    } else if (e < E0 + E1) {
        int i = e - E0;
        int d = d1[i];
        int old = atomicSub(&cnt1[d], 1);
        esrc1[off1[d] + old - 1] = s1[i];
    }
}

// ---------------- mean aggregation: one wave/target, 4 row-loads in flight ----------------
__global__ __launch_bounds__(256) void aggregate_kernel(const uint4* __restrict__ xb4,
        const int* __restrict__ esrc, const int* __restrict__ off,
        uint4* __restrict__ out4, int n_tgt) {
    const int lane = threadIdx.x & 63;
    const int half = lane >> 5, l31 = lane & 31;
    const int t = blockIdx.x * 4 + (threadIdx.x >> 6);
    if (t >= n_tgt) return;
    const int base = off[t];
    const int deg = off[t + 1] - base;
    float a[8] = {0.f, 0.f, 0.f, 0.f, 0.f, 0.f, 0.f, 0.f};
    int i = 0;
    for (; i + 4 <= deg; i += 4) {
        int s0 = esrc[base + i + half];
        int s1 = esrc[base + i + 2 + half];
        uint4 v0 = xb4[(size_t)s0 * 32 + l31];
        uint4 v1 = xb4[(size_t)s1 * 32 + l31];
        acc8(v0, a);
        acc8(v1, a);
    }
    for (; i + 2 <= deg; i += 2) {
        int s = esrc[base + i + half];
        uint4 v = xb4[(size_t)s * 32 + l31];
        acc8(v, a);
    }
    if ((deg & 1) && half == 0) {
        int s = esrc[base + deg - 1];
        uint4 v = xb4[(size_t)s * 32 + l31];
        acc8(v, a);
    }
#pragma unroll
    for (int j = 0; j < 8; ++j) a[j] += __shfl_xor(a[j], 32, 64);
    if (half == 0) {
        float inv = 1.0f / (float)(deg > 1 ? deg : 1);
        uint4 o;
        o.x = (uint32_t)f2bf(a[0] * inv) | ((uint32_t)f2bf(a[1] * inv) << 16);
        o.y = (uint32_t)f2bf(a[2] * inv) | ((uint32_t)f2bf(a[3] * inv) << 16);
        o.z = (uint32_t)f2bf(a[4] * inv) | ((uint32_t)f2bf(a[5] * inv) << 16);
        o.w = (uint32_t)f2bf(a[6] * inv) | ((uint32_t)f2bf(a[7] * inv) << 16);
        out4[(size_t)t * 32 + l31] = o;
    }
}

// ---------------- fallback: fp32 gather -> bf16 aggr ----------------
__global__ __launch_bounds__(256) void aggregate_f32_kernel(const float4* __restrict__ x4,
        const int* __restrict__ esrc, const int* __restrict__ off,
        uint2* __restrict__ aggr, int n_tgt) {
    int w = threadIdx.x >> 6;
    int lane = threadIdx.x & 63;
    int t = blockIdx.x * 4 + w;
    if (t >= n_tgt) return;
    int base = off[t];
    int deg = off[t + 1] - base;
    float4 acc = make_float4(0.f, 0.f, 0.f, 0.f);
    for (int i = 0; i < deg; ++i) {
        int s = esrc[base + i];
        float4 v = x4[(size_t)s * 64 + lane];
        acc.x += v.x; acc.y += v.y; acc.z += v.z; acc.w += v.w;
    }
    float inv = 1.0f / (float)(deg > 1 ? deg : 1);
    aggr[(size_t)t * 64 + lane] = pack4(acc.x * inv, acc.y * inv, acc.z * inv, acc.w * inv);
}

// ---------------- MFMA GEMM: h = relu([A|Axt] @ [Wl;Wr]^T + b), bf16 out + col stats ----------------
#define TM 128
#define TN 128
#define LDK 40

__global__ __launch_bounds__(256) void gemm_bn_mfma(
        const ushort* __restrict__ Aagg, const ushort* __restrict__ Axt,
        const ushort* __restrict__ Wl,  const ushort* __restrict__ Wr,
        const float* __restrict__ bias,
        ushort* __restrict__ h, float* __restrict__ colsum, float* __restrict__ colsq,
        int M) {
    __shared__ ushort As[TM * LDK];
    __shared__ ushort Bs[TN * LDK];
    __shared__ float csum[TN];
    __shared__ float csq[TN];

    const int tid = threadIdx.x;
    const int m0 = blockIdx.y * TM;
    const int n0 = blockIdx.x * TN;
    const int wid = tid >> 6, lane = tid & 63;
    const int l15 = lane & 15, quad = lane >> 4;
    const int wm = (wid & 1) * 64, wn = (wid >> 1) * 64;

    if (tid < TN) { csum[tid] = 0.f; csq[tid] = 0.f; }

    const int srow = tid >> 2;
    const int skoff = (tid & 3) * 8;

    f32x4 acc[4][4];
#pragma unroll
    for (int i = 0; i < 4; ++i)
#pragma unroll
        for (int j = 0; j < 4; ++j) acc[i][j] = (f32x4){0.f, 0.f, 0.f, 0.f};

#pragma unroll 1
    for (int kt = 0; kt < 16; ++kt) {
        const int ks = kt * 32;
        const ushort* Ab = (ks < 256) ? Aagg : Axt;
        const ushort* Bb = (ks < 256) ? Wl : Wr;
        const int k0 = ks & 255;
        int r0 = min(m0 + srow, M - 1);
        int r1 = min(m0 + srow + 64, M - 1);
        uint4 a0 = *(const uint4*)&Ab[(size_t)r0 * C + k0 + skoff];
        uint4 a1 = *(const uint4*)&Ab[(size_t)r1 * C + k0 + skoff];
        uint4 b0 = *(const uint4*)&Bb[(size_t)(n0 + srow) * C + k0 + skoff];
        uint4 b1 = *(const uint4*)&Bb[(size_t)(n0 + srow + 64) * C + k0 + skoff];
        __syncthreads();
        *(uint4*)&As[srow * LDK + skoff] = a0;
        *(uint4*)&As[(srow + 64) * LDK + skoff] = a1;
        *(uint4*)&Bs[srow * LDK + skoff] = b0;
        *(uint4*)&Bs[(srow + 64) * LDK + skoff] = b1;
        __syncthreads();

        short8 af[4], bw[4];
#pragma unroll
        for (int mi = 0; mi < 4; ++mi)
            af[mi] = *(const short8*)&As[(wm + mi * 16 + l15) * LDK + quad * 8];
#pragma unroll
        for (int ni = 0; ni < 4; ++ni)
            bw[ni] = *(const short8*)&Bs[(wn + ni * 16 + l15) * LDK + quad * 8];
#pragma unroll
        for (int mi = 0; mi < 4; ++mi)
#pragma unroll
            for (int ni = 0; ni < 4; ++ni)
                acc[mi][ni] = __builtin_amdgcn_mfma_f32_16x16x32_bf16(
                    af[mi], bw[ni], acc[mi][ni], 0, 0, 0);
    }

    float lsum[4] = {0.f, 0.f, 0.f, 0.f};
    float lsq[4]  = {0.f, 0.f, 0.f, 0.f};
#pragma unroll
    for (int ni = 0; ni < 4; ++ni) {
        const int col = wn + ni * 16 + l15;
        const float bv = bias[n0 + col];
#pragma unroll
        for (int mi = 0; mi < 4; ++mi) {
#pragma unroll
            for (int r = 0; r < 4; ++r) {
                int m = m0 + wm + mi * 16 + quad * 4 + r;
                float v = acc[mi][ni][r] + bv;
                v = fmaxf(v, 0.f);
                if (m < M) {
                    h[(size_t)m * C + n0 + col] = f2bf(v);
                    lsum[ni] += v;
                    lsq[ni] += v * v;
                }
            }
        }
    }
#pragma unroll
    for (int ni = 0; ni < 4; ++ni) {
        const int col = wn + ni * 16 + l15;
        atomicAdd(&csum[col], lsum[ni]);
        atomicAdd(&csq[col], lsq[ni]);
    }
    __syncthreads();
    if (tid < TN) {
        atomicAdd(&colsum[n0 + tid], csum[tid]);
        atomicAdd(&colsq[n0 + tid], csq[tid]);
    }
}

// ---------------- fixup: fold norm0 into layer-1 weights/bias ----------------
__global__ __launch_bounds__(256) void fixup_kernel(
        const float* __restrict__ colsum, const float* __restrict__ colsq, float invN,
        const float* __restrict__ g0, const float* __restrict__ be0,
        const float* __restrict__ Wl1, const float* __restrict__ Wr1,
        const float* __restrict__ bl1,
        ushort* __restrict__ wl1b, ushort* __restrict__ wr1b, float* __restrict__ bias1) {
    __shared__ float ss[C], st[C];
    __shared__ float red[256];
    const int k = threadIdx.x;
    {
        float m = colsum[k] * invN;
        float v = colsq[k] * invN - m * m;
        float r = rsqrtf(fmaxf(v, 0.f) + 1e-5f);
        float s = g0[k] * r;
        ss[k] = s;
        st[k] = be0[k] - m * s;
    }
    __syncthreads();
    const int n = blockIdx.x;
    float wl = Wl1[(size_t)n * C + k];
    float wr = Wr1[(size_t)n * C + k];
    wl1b[(size_t)n * C + k] = f2bf(wl * ss[k]);
    wr1b[(size_t)n * C + k] = f2bf(wr * ss[k]);
    red[k] = st[k] * (wl + wr);
    __syncthreads();
    for (int d = 128; d > 0; d >>= 1) {
        if (k < d) red[k] += red[k + d];
        __syncthreads();
    }
    if (k == 0) bias1[n] = bl1[n] + red[0];
}

// ---------------- norm1 (+ fused stat finalize): bf16 in -> fp32 out ----------------
__global__ __launch_bounds__(256) void norm1_kernel(const uint2* __restrict__ hin,
        const float* __restrict__ colsum, const float* __restrict__ colsq, float invN,
        const float* __restrict__ gamma, const float* __restrict__ beta,
        float4* __restrict__ outp, int n4) {
    __shared__ float smu[C], srs[C];
    {
        int k = threadIdx.x;
        float m = colsum[k] * invN;
        float v = colsq[k] * invN - m * m;
        smu[k] = m;
        srs[k] = rsqrtf(fmaxf(v, 0.f) + 1e-5f);
    }
    __syncthreads();
    int i = blockIdx.x * blockDim.x + threadIdx.x;
    if (i >= n4) return;
    int c = (i & 63) << 2;
    uint2 v = hin[i];
    float4 o;
    o.x = gamma[c + 0] * (bf2f((ushort)(v.x & 0xffff)) - smu[c + 0]) * srs[c + 0] + beta[c + 0];
    o.y = gamma[c + 1] * (bf2f((ushort)(v.x >> 16))    - smu[c + 1]) * srs[c + 1] + beta[c + 1];
    o.z = gamma[c + 2] * (bf2f((ushort)(v.y & 0xffff)) - smu[c + 2]) * srs[c + 2] + beta[c + 2];
    o.w = gamma[c + 3] * (bf2f((ushort)(v.y >> 16))    - smu[c + 3]) * srs[c + 3] + beta[c + 3];
    outp[i] = o;
}

extern "C" void kernel_launch(void* const* d_in, const int* in_sizes, int n_in,
                              void* d_out, int out_size, void* d_ws, size_t ws_size,
                              hipStream_t stream) {
    const float* x   = (const float*)d_in[0];
    const int* e0s   = (const int*)d_in[1];
    const int* e0d   = (const int*)d_in[2];
    const int* e1s   = (const int*)d_in[3];
    const int* e1d   = (const int*)d_in[4];
    const float* Wl0 = (const float*)d_in[5];
    const float* bl0 = (const float*)d_in[6];
    const float* Wr0 = (const float*)d_in[7];
    const float* ga0 = (const float*)d_in[8];
    const float* be0 = (const float*)d_in[9];
    const float* Wl1 = (const float*)d_in[10];
    const float* bl1 = (const float*)d_in[11];
    const float* Wr1 = (const float*)d_in[12];
    const float* ga1 = (const float*)d_in[13];
    const float* be1 = (const float*)d_in[14];

    const int N0 = 200000, N1 = 50000, N2 = 12500;
    const int E0 = in_sizes[1];
    const int E1 = in_sizes[3];

    char* ws = (char*)d_ws;
    size_t o = 0;
    auto alloc = [&](size_t bytes) -> char* {
        char* p = ws + o;
        o += (bytes + 255) & ~(size_t)255;
        return p;
    };

    const size_t common =
        (size_t)N1 * C * 2 * 2 + (size_t)E0 * 4 + (size_t)E1 * 4 +
        ((size_t)N1 + N2 + 8 * C) * 4 + ((size_t)N1 + N2 + 2) * 4 +
        4 * (size_t)C * C * 2 + C * 4 + 65536;
    const bool full = ws_size >= common + (size_t)N0 * C * 2;

    // zeroed region: cnt0 | cnt1 | stats (single memset)
    int* cnt0 = (int*)alloc(((size_t)N1 + N2 + 8 * C) * sizeof(int));
    int* cnt1 = cnt0 + N1;
    float* stats = (float*)(cnt1 + N2);
    float* colsum0 = stats,         *colsq0 = stats + C;
    float* colsum1 = stats + 4 * C, *colsq1 = stats + 5 * C;
    const size_t zbytes = ((size_t)N1 + N2 + 8 * C) * sizeof(int);

    int* off0 = (int*)alloc(((size_t)N1 + 1) * sizeof(int));
    int* off1 = (int*)alloc(((size_t)N2 + 1) * sizeof(int));
    ushort* x_bf  = (ushort*)alloc((full ? (size_t)N0 : (size_t)N1) * C * 2);
    ushort* aggr0 = (ushort*)alloc((size_t)N1 * C * 2);
    ushort* h0raw = (ushort*)alloc((size_t)N1 * C * 2);
    ushort* aggr1 = aggr0;                       // aggr0 dead after gemm0
    ushort* h1raw = aggr0 + (size_t)N2 * C;
    int* esrc0 = (int*)alloc((size_t)E0 * sizeof(int));
    int* esrc1 = (int*)alloc((size_t)E1 * sizeof(int));
    ushort* wbf = (ushort*)alloc(4 * (size_t)C * C * 2);
    ushort* wl0b = wbf, *wr0b = wbf + C * C, *wl1b = wbf + 2 * C * C, *wr1b = wbf + 3 * C * C;
    float* bias1 = (float*)alloc(C * sizeof(float));

    hipMemsetAsync(cnt0, 0, zbytes, stream);

    // prep: cast x + cast W0 + hist0 + hist1 (flat proportional grid)
    {
        int nx8 = (full ? N0 : N1) * C / 8;
        prep_kernel<<<PB_CAST + PB_W + PB_H0 + PB_H1, 256, 0, stream>>>(
            (const float4*)x, nx8, (uint4*)x_bf,
            (const float4*)Wl0, (const float4*)Wr0, (uint4*)wl0b, (uint4*)wr0b,
            e0d, cnt0, E0, e1d, cnt1, E1);
    }
    scan2_kernel<<<2, 1024, 0, stream>>>(cnt0, off0, N1, cnt1, off1, N2);
    scatter2_kernel<<<(E0 + E1 + 255) / 256, 256, 0, stream>>>(
        e0s, e0d, off0, cnt0, esrc0, E0, e1s, e1d, off1, cnt1, esrc1, E1);

    // ---------------- layer 0 ----------------
    if (full)
        aggregate_kernel<<<N1 / 4, 256, 0, stream>>>((const uint4*)x_bf, esrc0, off0,
                                                     (uint4*)aggr0, N1);
    else
        aggregate_f32_kernel<<<N1 / 4, 256, 0, stream>>>((const float4*)x, esrc0, off0,
                                                         (uint2*)aggr0, N1);
    dim3 grid0(C / TN, (N1 + TM - 1) / TM);
    gemm_bn_mfma<<<grid0, 256, 0, stream>>>(aggr0, x_bf, wl0b, wr0b, bl0,
                                            h0raw, colsum0, colsq0, N1);
    fixup_kernel<<<C, 256, 0, stream>>>(colsum0, colsq0, 1.0f / (float)N1,
                                        ga0, be0, Wl1, Wr1, bl1, wl1b, wr1b, bias1);

    // ---------------- layer 1 (operates on RAW h0) ----------------
    aggregate_kernel<<<N2 / 4, 256, 0, stream>>>((const uint4*)h0raw, esrc1, off1,
                                                 (uint4*)aggr1, N2);
    dim3 grid1(C / TN, (N2 + TM - 1) / TM);
    gemm_bn_mfma<<<grid1, 256, 0, stream>>>(aggr1, h0raw, wl1b, wr1b, bias1,
                                            h1raw, colsum1, colsq1, N2);
    int n4_1 = N2 * C / 4;
    norm1_kernel<<<(n4_1 + 255) / 256, 256, 0, stream>>>((const uint2*)h1raw,
                                                         colsum1, colsq1, 1.0f / (float)N2,
                                                         ga1, be1, (float4*)d_out, n4_1);
}